// Round 1
// baseline (185.612 us; speedup 1.0000x reference)
//
#include <hip/hip_runtime.h>
#include <stdint.h>

// B=4, S=2048, D=1024 self-attention, fp32 in/out.
// cvt(fp32->bf16, W^T) -> fused QKV GEMM -> scores GEMM (fp16 out, *1/32) ->
// softmax (fp16 in -> bf16 P) -> PV GEMM (fp32 out).
//
// r10: qkv + scores moved to a 512-thread BM256xBN256 BK32 ring-3 core with
// the 8-phase-style per-phase interleave (2 phases/K-tile, 16 MFMA each,
// stage one half-tile per phase, counted vmcnt(4) once per tile). This is
// the T3 regime gate the previous BM256xBN128 single-phase core lacked
// (m198/m201: same T1/T2/T4/T5 went 900->1563 TF only with the phase split).
//   qkv:    grid 384x512thr, 1 blk/CU (96KB LDS)
//   scores: grid 256x512thr, 1 blk/CU
//   pv:     unchanged old core (256thr BM256xBN128 ring-3, grid 256) -- at
//           BM256xBN256 pv would only fill 128/256 CUs.
// Workspace: [0,16M) X16 | [16,22M) TQ/TK/TV | [22,38M) Q16 | [38,54M) K16 |
//            [54,70M) VT [B][D][S] | [70,102M) SC16 fp16 | P16 aliases Q16+K16.

typedef __attribute__((ext_vector_type(8))) short bf16x8;
typedef __attribute__((ext_vector_type(4))) float f32x4;
typedef __attribute__((ext_vector_type(4))) unsigned short u16x4;
typedef __attribute__((ext_vector_type(8))) unsigned short u16x8;

__device__ __forceinline__ unsigned short f2bf(float f) {
  union { float f; unsigned u; } v; v.f = f;
  return (unsigned short)((v.u + 0x7FFFu + ((v.u >> 16) & 1u)) >> 16);
}
__device__ __forceinline__ unsigned short f2h(float f) {
  union { _Float16 h; unsigned short u; } v; v.h = (_Float16)f;
  return v.u;
}
__device__ __forceinline__ float h2f(unsigned short u) {
  union { unsigned short u; _Float16 h; } v; v.u = u;
  return (float)v.h;
}

__device__ __forceinline__ void gload16(const void* g, void* l) {
  __builtin_amdgcn_global_load_lds(
      (const __attribute__((address_space(1))) unsigned int*)g,
      (__attribute__((address_space(3))) unsigned int*)l, 16, 0, 0);
}

template <int N>
__device__ __forceinline__ void wait_vm() {
  asm volatile("s_waitcnt vmcnt(%0)" ::"n"(N) : "memory");
}

__device__ __forceinline__ int swz8(int bid, int cpx) {
  return (bid & 7) * cpx + (bid >> 3);  // bijective when nwg%8==0
}

__device__ __forceinline__ f32x4 mfma16(bf16x8 a, bf16x8 b, f32x4 c) {
  return __builtin_amdgcn_mfma_f32_16x16x32_bf16(a, b, c, 0, 0, 0);
}

// ================= NEW core: 512 thr, BM256 x BN256, BK=32, ring-3 =========
// 8 waves as 2(M) x 4(N); wave tile 128x64 (MF=8, NF=4).  Slot = 32KB
// (A 256x32 + B 256x32 bf16), ring-3 = 96KB.  Per K-tile: 2 phases of
// 16 MFMA; phase 0 stages A-half of tile t+2, phase 1 stages B-half +
// counted vmcnt(4).  Safety: slot (t+2)%3 == (t-1)%3 was last read in iter
// t-1 (barrier-ordered); vmcnt(4) before the phase-1 barrier guarantees all
// waves' tile-t+1 loads landed before iter t+1 reads them.
__device__ __forceinline__ void gemm_core2(
    const unsigned short* __restrict__ A, const unsigned short* __restrict__ Bt,
    const int lda, const int ldb, const int nt,
    const long aRow0, const long bRow0, char* lds,
    f32x4 (&acc)[8][4]) {
  constexpr int A_BYTES = 256 * 64;  // 16KB
  constexpr int SLOT = 2 * A_BYTES;  // 32KB
  const int tid = threadIdx.x;
  const int lane = tid & 63;
  const int wid = tid >> 6;
  const int wm = wid >> 2, wn = wid & 3;
  const int l15 = lane & 15, lhi = lane >> 4;

  // staging: LDS dest linear (global_load_lds requirement), global source
  // pre-swizzled so LDS (row, ch) holds global (row, ch ^ ((row>>1)&3)).
  long goffA[2]; int ldsoffA[2];
#pragma unroll
  for (int j = 0; j < 2; ++j) {
    const int local = j * 8192 + tid * 16;
    const int row = local >> 6, ch = (local >> 4) & 3;
    goffA[j] = (aRow0 + row) * (long)lda + ((ch ^ ((row >> 1) & 3)) << 3);
    ldsoffA[j] = local;
  }
  long goffB[2]; int ldsoffB[2];
#pragma unroll
  for (int j = 0; j < 2; ++j) {
    const int local = j * 8192 + tid * 16;
    const int row = local >> 6, ch = (local >> 4) & 3;
    goffB[j] = (bRow0 + row) * (long)ldb + ((ch ^ ((row >> 1) & 3)) << 3);
    ldsoffB[j] = A_BYTES + local;
  }
  // swizzled LDS read byte-offsets (within slot)
  int raddrA[8];
#pragma unroll
  for (int m = 0; m < 8; ++m) {
    const int row = wm * 128 + m * 16 + l15;
    raddrA[m] = row * 64 + ((lhi ^ ((row >> 1) & 3)) << 4);
  }
  int raddrB[4];
#pragma unroll
  for (int n = 0; n < 4; ++n) {
    const int row = wn * 64 + n * 16 + l15;
    raddrB[n] = A_BYTES + row * 64 + ((lhi ^ ((row >> 1) & 3)) << 4);
  }

  const f32x4 z4 = {0.f, 0.f, 0.f, 0.f};
#pragma unroll
  for (int m = 0; m < 8; ++m)
#pragma unroll
    for (int n = 0; n < 4; ++n) acc[m][n] = z4;

  auto stage_A = [&](int T) {
    char* dst = lds + (T % 3) * SLOT;
    const int k0 = T << 5;
#pragma unroll
    for (int j = 0; j < 2; ++j) gload16(A + goffA[j] + k0, dst + ldsoffA[j]);
  };
  auto stage_B = [&](int T) {
    char* dst = lds + (T % 3) * SLOT;
    const int k0 = T << 5;
#pragma unroll
    for (int j = 0; j < 2; ++j) gload16(Bt + goffB[j] + k0, dst + ldsoffB[j]);
  };

  // prologue: stage tiles 0,1; wait tile 0 (leave tile 1 in flight)
  stage_A(0); stage_B(0);
  stage_A(1); stage_B(1);
  wait_vm<4>();
  __builtin_amdgcn_s_barrier();

  for (int t = 0; t < nt; ++t) {
    const char* sb = lds + (t % 3) * SLOT;
    bf16x8 af[4], af2[4], bfr[4];
    // ---- phase 0: read B + A(m0..3), stage A-half of t+2, MFMA m0..3
#pragma unroll
    for (int n = 0; n < 4; ++n) bfr[n] = *(const bf16x8*)(sb + raddrB[n]);
#pragma unroll
    for (int m = 0; m < 4; ++m) af[m] = *(const bf16x8*)(sb + raddrA[m]);
    if (t + 2 < nt) stage_A(t + 2);
    __builtin_amdgcn_s_barrier();
    __builtin_amdgcn_s_setprio(1);
#pragma unroll
    for (int m = 0; m < 4; ++m)
#pragma unroll
      for (int n = 0; n < 4; ++n) acc[m][n] = mfma16(af[m], bfr[n], acc[m][n]);
    __builtin_amdgcn_s_setprio(0);
    __builtin_amdgcn_s_barrier();
    // ---- phase 1: read A(m4..7), stage B-half of t+2, counted vmcnt, MFMA
#pragma unroll
    for (int m = 0; m < 4; ++m) af2[m] = *(const bf16x8*)(sb + raddrA[4 + m]);
    if (t + 2 < nt) {
      stage_B(t + 2);
      wait_vm<4>();  // tile t+1 fully landed; t+2's 4 loads stay in flight
    } else if (t + 1 < nt) {
      wait_vm<0>();  // epilogue drain
    }
    __builtin_amdgcn_s_barrier();
    __builtin_amdgcn_s_setprio(1);
#pragma unroll
    for (int m = 0; m < 4; ++m)
#pragma unroll
      for (int n = 0; n < 4; ++n)
        acc[4 + m][n] = mfma16(af2[m], bfr[n], acc[4 + m][n]);
    __builtin_amdgcn_s_setprio(0);
    __builtin_amdgcn_s_barrier();
  }
}

// ================= OLD core (kept for pv): 256 thr, BM256 x BN128 ==========
__device__ __forceinline__ void gemm_core(
    const unsigned short* __restrict__ A, const unsigned short* __restrict__ Bt,
    const int lda, const int ldb, const int nt,
    const long aRow0, const long bRow0, char* lds,
    f32x4 (&acc)[8][4]) {
  constexpr int A_BYTES = 256 * 64;           // 16KB
  constexpr int SLOT = A_BYTES + 128 * 64;    // 24KB
  constexpr int LA = 4, LB = 2, L = LA + LB;  // 16B gloads per thread per tile
  const int tid = threadIdx.x;
  const int lane = tid & 63;
  const int wid = tid >> 6;
  const int wm = wid >> 1, wn = wid & 1;
  const int l15 = lane & 15, lhi = lane >> 4;

  long goffA[LA]; int ldsoffA[LA];
#pragma unroll
  for (int j = 0; j < LA; ++j) {
    const int local = j * 4096 + tid * 16;
    const int row = local >> 6, ch = (local >> 4) & 3;
    goffA[j] = (aRow0 + row) * (long)lda + ((ch ^ ((row >> 1) & 3)) << 3);
    ldsoffA[j] = local;
  }
  long goffB[LB]; int ldsoffB[LB];
#pragma unroll
  for (int j = 0; j < LB; ++j) {
    const int local = j * 4096 + tid * 16;
    const int row = local >> 6, ch = (local >> 4) & 3;
    goffB[j] = (bRow0 + row) * (long)ldb + ((ch ^ ((row >> 1) & 3)) << 3);
    ldsoffB[j] = A_BYTES + local;
  }
  int raddrA[8];
#pragma unroll
  for (int m = 0; m < 8; ++m) {
    const int row = wm * 128 + m * 16 + l15;
    raddrA[m] = row * 64 + ((lhi ^ ((row >> 1) & 3)) << 4);
  }
  int raddrB[4];
#pragma unroll
  for (int n = 0; n < 4; ++n) {
    const int row = wn * 64 + n * 16 + l15;
    raddrB[n] = A_BYTES + row * 64 + ((lhi ^ ((row >> 1) & 3)) << 4);
  }

  const f32x4 z4 = {0.f, 0.f, 0.f, 0.f};
#pragma unroll
  for (int m = 0; m < 8; ++m)
#pragma unroll
    for (int n = 0; n < 4; ++n) acc[m][n] = z4;

  auto stage_tile = [&](int T) {
    char* dst = lds + (T % 3) * SLOT;
    const int k0 = T << 5;
#pragma unroll
    for (int j = 0; j < LA; ++j) gload16(A + goffA[j] + k0, dst + ldsoffA[j]);
#pragma unroll
    for (int j = 0; j < LB; ++j) gload16(Bt + goffB[j] + k0, dst + ldsoffB[j]);
  };

  stage_tile(0);
  stage_tile(1);
  wait_vm<L>();
  __builtin_amdgcn_s_barrier();

  for (int t = 0; t < nt; ++t) {
    const char* sb = lds + (t % 3) * SLOT;
    bf16x8 af[8], bfr[4];
#pragma unroll
    for (int n = 0; n < 4; ++n) bfr[n] = *(const bf16x8*)(sb + raddrB[n]);
#pragma unroll
    for (int m = 0; m < 8; ++m) af[m] = *(const bf16x8*)(sb + raddrA[m]);
    if (t + 2 < nt) stage_tile(t + 2);
    __builtin_amdgcn_s_setprio(1);
#pragma unroll
    for (int m = 0; m < 8; ++m)
#pragma unroll
      for (int n = 0; n < 4; ++n) acc[m][n] = mfma16(af[m], bfr[n], acc[m][n]);
    __builtin_amdgcn_s_setprio(0);
    if (t + 2 < nt) wait_vm<L>();
    else if (t + 1 < nt) wait_vm<0>();
    __builtin_amdgcn_s_barrier();
  }
}

// ---- fused QKV: X[8192,1024] x {Wq,Wk,Wv}^T. BM256xBN256, grid 384x512.
__global__ __launch_bounds__(512, 2) void qkv_kernel(
    const unsigned short* __restrict__ X, const unsigned short* __restrict__ TQ,
    const unsigned short* __restrict__ TK, const unsigned short* __restrict__ TV,
    const float* __restrict__ bq, const float* __restrict__ bk,
    const float* __restrict__ bv, unsigned short* __restrict__ Q16,
    unsigned short* __restrict__ K16, unsigned short* __restrict__ VT) {
  __shared__ char lds[3 * 32768];
  const int wgid = swz8(blockIdx.x, 48);
  const int tm = wgid / 12, tn = wgid % 12;
  const int w = tn >> 2, c = tn & 3;
  const unsigned short* Bt = w == 0 ? TQ : (w == 1 ? TK : TV);
  const float* bias = w == 0 ? bq : (w == 1 ? bk : bv);

  f32x4 acc[8][4];
  gemm_core2(X, Bt, 1024, 1024, 32, (long)tm * 256, (long)c * 256, lds, acc);

  const int tid = threadIdx.x, lane = tid & 63, wid = tid >> 6;
  const int wm = wid >> 2, wn = wid & 3;
  const int l15 = lane & 15, lhi = lane >> 4;
  const int rowBase = tm * 256 + wm * 128;
  const int colBase = c * 256 + wn * 64;  // within-weight column (D index)
  if (w < 2) {
    unsigned short* C = w == 0 ? Q16 : K16;
#pragma unroll
    for (int m = 0; m < 8; ++m)
#pragma unroll
      for (int n = 0; n < 4; ++n) {
        const int col = colBase + n * 16 + l15;
        const float bvv = bias[col];
#pragma unroll
        for (int j = 0; j < 4; ++j) {
          const int row = rowBase + m * 16 + lhi * 4 + j;
          C[(long)row * 1024 + col] = f2bf(acc[m][n][j] + bvv);
        }
      }
  } else {
#pragma unroll
    for (int m = 0; m < 8; ++m)
#pragma unroll
      for (int n = 0; n < 4; ++n) {
        const int col = colBase + n * 16 + l15;
        const float bvv = bias[col];
        const int row0 = rowBase + m * 16 + lhi * 4;
        const int b = row0 >> 11, s = row0 & 2047;
        u16x4 v;
#pragma unroll
        for (int j = 0; j < 4; ++j) v[j] = f2bf(acc[m][n][j] + bvv);
        *reinterpret_cast<u16x4*>(&VT[(long)b * 2097152 + (long)col * 2048 + s]) = v;
      }
  }
}

// ---- scores = Q K^T / 32 per batch, fp16 out. BM256xBN256, grid 256x512.
__global__ __launch_bounds__(512, 2) void scores_kernel(
    const unsigned short* __restrict__ Q16, const unsigned short* __restrict__ K16,
    unsigned short* __restrict__ SC16) {
  __shared__ char lds[3 * 32768];
  const int wgid = swz8(blockIdx.x, 32);
  const int bz = wgid >> 6, tm = (wgid >> 3) & 7, tn = wgid & 7;
  const unsigned short* A = Q16 + (long)bz * 2097152;
  const unsigned short* Bt = K16 + (long)bz * 2097152;

  f32x4 acc[8][4];
  gemm_core2(A, Bt, 1024, 1024, 32, (long)tm * 256, (long)tn * 256, lds, acc);

  unsigned short* C = SC16 + (long)bz * 4194304;
  const int tid = threadIdx.x, lane = tid & 63, wid = tid >> 6;
  const int wm = wid >> 2, wn = wid & 3;
  const int l15 = lane & 15, lhi = lane >> 4;
  const int rowBase = tm * 256 + wm * 128;
  const int colBase = tn * 256 + wn * 64;
#pragma unroll
  for (int m = 0; m < 8; ++m)
#pragma unroll
    for (int n = 0; n < 4; ++n) {
      const int col = colBase + n * 16 + l15;
#pragma unroll
      for (int j = 0; j < 4; ++j) {
        const int row = rowBase + m * 16 + lhi * 4 + j;
        C[(long)row * 2048 + col] = f2h(acc[m][n][j] * (1.f / 32.f));
      }
    }
}

// ---- out = P V per batch (Bt = VT[D][S]). BM256xBN128, grid 256x256.
__global__ __launch_bounds__(256, 2) void pv_kernel(
    const unsigned short* __restrict__ P16, const unsigned short* __restrict__ VT,
    float* __restrict__ out) {
  __shared__ char lds[3 * 24576];
  const int wgid = swz8(blockIdx.x, 32);
  const int bz = wgid >> 6, tm = (wgid >> 3) & 7, tn = wgid & 7;
  const unsigned short* A = P16 + (long)bz * 4194304;
  const unsigned short* Bt = VT + (long)bz * 2097152;

  f32x4 acc[8][4];
  gemm_core(A, Bt, 2048, 2048, 64, (long)tm * 256, (long)tn * 128, lds, acc);

  float* C = out + (long)bz * 2097152;
  const int tid = threadIdx.x, lane = tid & 63, wid = tid >> 6;
  const int wm = wid >> 1, wn = wid & 1;
  const int l15 = lane & 15, lhi = lane >> 4;
  const int rowBase = tm * 256 + wm * 128;
  const int colBase = tn * 128 + wn * 64;
#pragma unroll
  for (int m = 0; m < 8; ++m)
#pragma unroll
    for (int n = 0; n < 4; ++n) {
      const int col = colBase + n * 16 + l15;
#pragma unroll
      for (int j = 0; j < 4; ++j) {
        const int row = rowBase + m * 16 + lhi * 4 + j;
        C[(long)row * 1024 + col] = acc[m][n][j];
      }
    }
}

// ---- fp32 -> bf16, 4 elems/thread ----
__global__ __launch_bounds__(256) void cvt4(const float* __restrict__ in,
                                            unsigned short* __restrict__ out) {
  int i = blockIdx.x * 256 + threadIdx.x;
  float4 v = reinterpret_cast<const float4*>(in)[i];
  u16x4 r;
  r[0] = f2bf(v.x); r[1] = f2bf(v.y); r[2] = f2bf(v.z); r[3] = f2bf(v.w);
  reinterpret_cast<u16x4*>(out)[i] = r;
}

// ---- W [K,N] fp32 -> Wt [N,K] bf16 ----
__global__ __launch_bounds__(256) void cvtWt(
    const float* __restrict__ w0, const float* __restrict__ w1, const float* __restrict__ w2,
    unsigned short* __restrict__ t0, unsigned short* __restrict__ t1, unsigned short* __restrict__ t2) {
  const float* w = blockIdx.y == 0 ? w0 : (blockIdx.y == 1 ? w1 : w2);
  unsigned short* t = blockIdx.y == 0 ? t0 : (blockIdx.y == 1 ? t1 : t2);
  int id = blockIdx.x * 256 + threadIdx.x;
  int k = id >> 10, n = id & 1023;
  t[n * 1024 + k] = f2bf(w[id]);
}

// ---- row softmax: fp16 scores -> bf16 P.  One block per row (8 elems/thr).
__global__ __launch_bounds__(256) void softmax_rows(const unsigned short* __restrict__ S,
                                                    unsigned short* __restrict__ P) {
  const long row = blockIdx.x;
  const u16x8* src = reinterpret_cast<const u16x8*>(S + row * 2048);
  const int tid = threadIdx.x;
  u16x8 a = src[tid];
  float v[8];
#pragma unroll
  for (int i = 0; i < 8; ++i) v[i] = h2f(a[i]);
  float m = v[0];
#pragma unroll
  for (int i = 1; i < 8; ++i) m = fmaxf(m, v[i]);
#pragma unroll
  for (int o = 32; o > 0; o >>= 1) m = fmaxf(m, __shfl_xor(m, o));
  __shared__ float red[8];
  const int wid = tid >> 6, lane = tid & 63;
  if (lane == 0) red[wid] = m;
  __syncthreads();
  m = fmaxf(fmaxf(red[0], red[1]), fmaxf(red[2], red[3]));
  float s = 0.f;
#pragma unroll
  for (int i = 0; i < 8; ++i) { v[i] = __expf(v[i] - m); s += v[i]; }
#pragma unroll
  for (int o = 32; o > 0; o >>= 1) s += __shfl_xor(s, o);
  if (lane == 0) red[4 + wid] = s;
  __syncthreads();
  s = (red[4] + red[5]) + (red[6] + red[7]);
  const float inv = 1.f / s;
  u16x8 p;
#pragma unroll
  for (int i = 0; i < 8; ++i) p[i] = f2bf(v[i] * inv);
  reinterpret_cast<u16x8*>(P + row * 2048)[tid] = p;
}

extern "C" void kernel_launch(void* const* d_in, const int* in_sizes, int n_in,
                              void* d_out, int out_size, void* d_ws, size_t ws_size,
                              hipStream_t stream) {
  const float* x  = (const float*)d_in[0];
  const float* Wq = (const float*)d_in[1];
  const float* bq = (const float*)d_in[2];
  const float* Wk = (const float*)d_in[3];
  const float* bk = (const float*)d_in[4];
  const float* Wv = (const float*)d_in[5];
  const float* bv = (const float*)d_in[6];
  float* out = (float*)d_out;

  char* ws = (char*)d_ws;
  const size_t MB = 1024 * 1024;
  unsigned short* X16 = (unsigned short*)(ws);
  unsigned short* TQ  = (unsigned short*)(ws + 16 * MB);
  unsigned short* TK  = (unsigned short*)(ws + 18 * MB);
  unsigned short* TV  = (unsigned short*)(ws + 20 * MB);
  unsigned short* Q16 = (unsigned short*)(ws + 22 * MB);
  unsigned short* K16 = (unsigned short*)(ws + 38 * MB);
  unsigned short* VT  = (unsigned short*)(ws + 54 * MB);
  unsigned short* SC16 = (unsigned short*)(ws + 70 * MB);
  unsigned short* P16 = Q16;  // alias Q16+K16 (32MB), dead after scores GEMM

  cvt4<<<8192, 256, 0, stream>>>(x, X16);
  cvtWt<<<dim3(4096, 3), 256, 0, stream>>>(Wq, Wk, Wv, TQ, TK, TV);

  qkv_kernel<<<384, 512, 0, stream>>>(X16, TQ, TK, TV, bq, bk, bv, Q16, K16, VT);
  scores_kernel<<<256, 512, 0, stream>>>(Q16, K16, SC16);
  softmax_rows<<<4 * 2048, 256, 0, stream>>>(SC16, P16);
  pv_kernel<<<256, 256, 0, stream>>>(P16, VT, out);

  (void)in_sizes; (void)n_in; (void)out_size; (void)ws_size;
}

// Round 2
// 174.298 us; speedup vs baseline: 1.0649x; 1.0649x over previous
//
#include <hip/hip_runtime.h>
#include <stdint.h>

// B=4, S=2048, D=1024 self-attention, fp32 in/out.
// cvt(fp32->bf16, W^T) -> fused QKV GEMM -> scores GEMM (fp16 out, *1/32) ->
// softmax (fp16 in -> bf16 P) -> PV GEMM (fp32 out).
//
// r11: qkv/pv reverted to the r6-proven 256-thr BM256xBN128 ring-3 core
// (r10's 2-phase graft regressed qkv 64->77us; VGPR-capped + BK=32 + bad
// grid fit). scores alone moves to a faithful m201-style core: 512 thr,
// BM=BN=256, BK=64, double-buffered 128KB dynamic LDS, 4 phases/K-tile,
// counted vmcnt(4) twice per tile, launch_bounds(512,1) (256-VGPR budget).
// scores grid = 256 blocks = exactly 1/CU, no tail: ideal host for the
// template. Single-variable experiment.
// Workspace: [0,16M) X16 | [16,22M) TQ/TK/TV | [22,38M) Q16 | [38,54M) K16 |
//            [54,70M) VT [B][D][S] | [70,102M) SC16 fp16 | P16 aliases Q16+K16.

typedef __attribute__((ext_vector_type(8))) short bf16x8;
typedef __attribute__((ext_vector_type(4))) float f32x4;
typedef __attribute__((ext_vector_type(4))) unsigned short u16x4;
typedef __attribute__((ext_vector_type(8))) unsigned short u16x8;

__device__ __forceinline__ unsigned short f2bf(float f) {
  union { float f; unsigned u; } v; v.f = f;
  return (unsigned short)((v.u + 0x7FFFu + ((v.u >> 16) & 1u)) >> 16);
}
__device__ __forceinline__ unsigned short f2h(float f) {
  union { _Float16 h; unsigned short u; } v; v.h = (_Float16)f;
  return v.u;
}
__device__ __forceinline__ float h2f(unsigned short u) {
  union { unsigned short u; _Float16 h; } v; v.u = u;
  return (float)v.h;
}

__device__ __forceinline__ void gload16(const void* g, void* l) {
  __builtin_amdgcn_global_load_lds(
      (const __attribute__((address_space(1))) unsigned int*)g,
      (__attribute__((address_space(3))) unsigned int*)l, 16, 0, 0);
}

template <int N>
__device__ __forceinline__ void wait_vm() {
  asm volatile("s_waitcnt vmcnt(%0)" ::"n"(N) : "memory");
}

__device__ __forceinline__ int swz8(int bid, int cpx) {
  return (bid & 7) * cpx + (bid >> 3);  // bijective when nwg%8==0
}

__device__ __forceinline__ f32x4 mfma16(bf16x8 a, bf16x8 b, f32x4 c) {
  return __builtin_amdgcn_mfma_f32_16x16x32_bf16(a, b, c, 0, 0, 0);
}

// ================= r6-proven core: 256 thr, BM256 x BN128, ring-3 ==========
__device__ __forceinline__ void gemm_core(
    const unsigned short* __restrict__ A, const unsigned short* __restrict__ Bt,
    const int lda, const int ldb, const int nt,
    const long aRow0, const long bRow0, char* lds,
    f32x4 (&acc)[8][4]) {
  constexpr int A_BYTES = 256 * 64;           // 16KB
  constexpr int SLOT = A_BYTES + 128 * 64;    // 24KB
  constexpr int LA = 4, LB = 2, L = LA + LB;  // 16B gloads per thread per tile
  const int tid = threadIdx.x;
  const int lane = tid & 63;
  const int wid = tid >> 6;
  const int wm = wid >> 1, wn = wid & 1;
  const int l15 = lane & 15, lhi = lane >> 4;

  long goffA[LA]; int ldsoffA[LA];
#pragma unroll
  for (int j = 0; j < LA; ++j) {
    const int local = j * 4096 + tid * 16;
    const int row = local >> 6, ch = (local >> 4) & 3;
    goffA[j] = (aRow0 + row) * (long)lda + ((ch ^ ((row >> 1) & 3)) << 3);
    ldsoffA[j] = local;
  }
  long goffB[LB]; int ldsoffB[LB];
#pragma unroll
  for (int j = 0; j < LB; ++j) {
    const int local = j * 4096 + tid * 16;
    const int row = local >> 6, ch = (local >> 4) & 3;
    goffB[j] = (bRow0 + row) * (long)ldb + ((ch ^ ((row >> 1) & 3)) << 3);
    ldsoffB[j] = A_BYTES + local;
  }
  int raddrA[8];
#pragma unroll
  for (int m = 0; m < 8; ++m) {
    const int row = wm * 128 + m * 16 + l15;
    raddrA[m] = row * 64 + ((lhi ^ ((row >> 1) & 3)) << 4);
  }
  int raddrB[4];
#pragma unroll
  for (int n = 0; n < 4; ++n) {
    const int row = wn * 64 + n * 16 + l15;
    raddrB[n] = A_BYTES + row * 64 + ((lhi ^ ((row >> 1) & 3)) << 4);
  }

  const f32x4 z4 = {0.f, 0.f, 0.f, 0.f};
#pragma unroll
  for (int m = 0; m < 8; ++m)
#pragma unroll
    for (int n = 0; n < 4; ++n) acc[m][n] = z4;

  auto stage_tile = [&](int T) {
    char* dst = lds + (T % 3) * SLOT;
    const int k0 = T << 5;
#pragma unroll
    for (int j = 0; j < LA; ++j) gload16(A + goffA[j] + k0, dst + ldsoffA[j]);
#pragma unroll
    for (int j = 0; j < LB; ++j) gload16(Bt + goffB[j] + k0, dst + ldsoffB[j]);
  };

  stage_tile(0);
  stage_tile(1);
  wait_vm<L>();
  __builtin_amdgcn_s_barrier();

  for (int t = 0; t < nt; ++t) {
    const char* sb = lds + (t % 3) * SLOT;
    bf16x8 af[8], bfr[4];
#pragma unroll
    for (int n = 0; n < 4; ++n) bfr[n] = *(const bf16x8*)(sb + raddrB[n]);
#pragma unroll
    for (int m = 0; m < 8; ++m) af[m] = *(const bf16x8*)(sb + raddrA[m]);
    if (t + 2 < nt) stage_tile(t + 2);
    __builtin_amdgcn_s_setprio(1);
#pragma unroll
    for (int m = 0; m < 8; ++m)
#pragma unroll
      for (int n = 0; n < 4; ++n) acc[m][n] = mfma16(af[m], bfr[n], acc[m][n]);
    __builtin_amdgcn_s_setprio(0);
    if (t + 2 < nt) wait_vm<L>();
    else if (t + 1 < nt) wait_vm<0>();
    __builtin_amdgcn_s_barrier();
  }
}

// ====== m201-style core: 512 thr, BM=BN=256, BK=64, double-buffer ==========
// LDS per slot: A[kk=2][256 rows][32 bf16] (32KB) + B[2][256][32] (32KB);
// 2 slots = 128KB (dynamic).  8 waves as 2(M)x4(N), wave tile 128x64.
// Per K-tile: 4 phases x 16 MFMA (quadrant = m-half x kk).  Each phase
// stages one quarter (2 gloads/thr) of tile t+1 into slot^1.
// vmcnt(4) twice per tile; wait algebra (steady state, loads in 2-groups):
//   end P2: outstanding {A1(t),B1(t),A0(t+1),B0(t+1)}=8 -> vmcnt(4)
//           retires A1,B1(t) needed by P3/P4 reads.
//   end P4: outstanding {A0,B0,A1,B1}(t+1)=8 -> vmcnt(4) retires
//           A0,B0(t+1) needed by next iter P1/P2 reads.
// Never drains to 0 mid-loop (m218: counted-vs-drain0 = +38..73%).
__device__ __forceinline__ void gemm_core3(
    const unsigned short* __restrict__ A, const unsigned short* __restrict__ Bt,
    const int lda, const int ldb, const int nt64,
    const long aRow0, const long bRow0, char* lds,
    f32x4 (&acc)[8][4]) {
  constexpr int SLICE = 256 * 64;     // 16KB: one kk-slice, 256 rows x 64B
  constexpr int A_BYTES = 2 * SLICE;  // 32KB
  constexpr int SLOT = 2 * A_BYTES;   // 64KB
  const int tid = threadIdx.x;
  const int lane = tid & 63;
  const int wid = tid >> 6;
  const int wm = wid >> 2, wn = wid & 3;
  const int l15 = lane & 15, lhi = lane >> 4;

  // staging offsets: 2 x 16B loads per thread per 16KB slice-group.
  // LDS dest linear; global source pre-swizzled (ch ^ ((row>>1)&3)).
  long goffA[2][2], goffB[2][2];  // [kk][j]
  int ldsoff[2];
#pragma unroll
  for (int j = 0; j < 2; ++j) {
    const int local = j * 8192 + tid * 16;
    const int row = local >> 6, ch = (local >> 4) & 3;
    ldsoff[j] = local;
    const int kalt = (ch ^ ((row >> 1) & 3)) << 3;
#pragma unroll
    for (int kk = 0; kk < 2; ++kk) {
      goffA[kk][j] = (aRow0 + row) * (long)lda + kk * 32 + kalt;
      goffB[kk][j] = (bRow0 + row) * (long)ldb + kk * 32 + kalt;
    }
  }
  // swizzled read offsets within a slice
  int raddrA[8];
#pragma unroll
  for (int m = 0; m < 8; ++m) {
    const int row = wm * 128 + m * 16 + l15;
    raddrA[m] = row * 64 + ((lhi ^ ((row >> 1) & 3)) << 4);
  }
  int raddrB[4];
#pragma unroll
  for (int n = 0; n < 4; ++n) {
    const int row = wn * 64 + n * 16 + l15;
    raddrB[n] = row * 64 + ((lhi ^ ((row >> 1) & 3)) << 4);
  }

  const f32x4 z4 = {0.f, 0.f, 0.f, 0.f};
#pragma unroll
  for (int m = 0; m < 8; ++m)
#pragma unroll
    for (int n = 0; n < 4; ++n) acc[m][n] = z4;

  auto stageA = [&](int s, int kk, int T) {
    char* dst = lds + s * SLOT + kk * SLICE;
    const long k0 = (long)T << 6;
#pragma unroll
    for (int j = 0; j < 2; ++j) gload16(A + goffA[kk][j] + k0, dst + ldsoff[j]);
  };
  auto stageB = [&](int s, int kk, int T) {
    char* dst = lds + s * SLOT + A_BYTES + kk * SLICE;
    const long k0 = (long)T << 6;
#pragma unroll
    for (int j = 0; j < 2; ++j) gload16(Bt + goffB[kk][j] + k0, dst + ldsoff[j]);
  };

  // prologue: all 4 quarters of tile 0; A0,B0 must land, A1,B1 stay in flight
  stageA(0, 0, 0); stageB(0, 0, 0);
  stageA(0, 1, 0); stageB(0, 1, 0);
  wait_vm<4>();
  __builtin_amdgcn_s_barrier();

  int cur = 0;
  for (int t = 0; t < nt64; ++t) {
    const char* sb = lds + cur * SLOT;
    const int nxt = cur ^ 1;
    const bool pf = (t + 1 < nt64);
    bf16x8 a0[4], a1[4], b0[4], b1[4];
    // ---- P1: read B(kk0) + A(m0..3,kk0); stage A-slice0(t+1)
#pragma unroll
    for (int n = 0; n < 4; ++n) b0[n] = *(const bf16x8*)(sb + A_BYTES + raddrB[n]);
#pragma unroll
    for (int m = 0; m < 4; ++m) a0[m] = *(const bf16x8*)(sb + raddrA[m]);
    if (pf) stageA(nxt, 0, t + 1);
    __builtin_amdgcn_s_barrier();
    __builtin_amdgcn_s_setprio(1);
#pragma unroll
    for (int m = 0; m < 4; ++m)
#pragma unroll
      for (int n = 0; n < 4; ++n) acc[m][n] = mfma16(a0[m], b0[n], acc[m][n]);
    __builtin_amdgcn_s_setprio(0);
    __builtin_amdgcn_s_barrier();
    // ---- P2: read A(m4..7,kk0); stage B-slice0(t+1); counted vmcnt
#pragma unroll
    for (int m = 0; m < 4; ++m) a1[m] = *(const bf16x8*)(sb + raddrA[4 + m]);
    if (pf) { stageB(nxt, 0, t + 1); wait_vm<4>(); }
    else wait_vm<0>();  // last tile: ensure own slice-1 resident for P3
    __builtin_amdgcn_s_barrier();
    __builtin_amdgcn_s_setprio(1);
#pragma unroll
    for (int m = 0; m < 4; ++m)
#pragma unroll
      for (int n = 0; n < 4; ++n)
        acc[4 + m][n] = mfma16(a1[m], b0[n], acc[4 + m][n]);
    __builtin_amdgcn_s_setprio(0);
    __builtin_amdgcn_s_barrier();
    // ---- P3: read B(kk1) + A(m0..3,kk1); stage A-slice1(t+1)
#pragma unroll
    for (int n = 0; n < 4; ++n)
      b1[n] = *(const bf16x8*)(sb + A_BYTES + SLICE + raddrB[n]);
#pragma unroll
    for (int m = 0; m < 4; ++m) a0[m] = *(const bf16x8*)(sb + SLICE + raddrA[m]);
    if (pf) stageA(nxt, 1, t + 1);
    __builtin_amdgcn_s_barrier();
    __builtin_amdgcn_s_setprio(1);
#pragma unroll
    for (int m = 0; m < 4; ++m)
#pragma unroll
      for (int n = 0; n < 4; ++n) acc[m][n] = mfma16(a0[m], b1[n], acc[m][n]);
    __builtin_amdgcn_s_setprio(0);
    __builtin_amdgcn_s_barrier();
    // ---- P4: read A(m4..7,kk1); stage B-slice1(t+1); counted vmcnt
#pragma unroll
    for (int m = 0; m < 4; ++m)
      a1[m] = *(const bf16x8*)(sb + SLICE + raddrA[4 + m]);
    if (pf) { stageB(nxt, 1, t + 1); wait_vm<4>(); }
    __builtin_amdgcn_s_barrier();
    __builtin_amdgcn_s_setprio(1);
#pragma unroll
    for (int m = 0; m < 4; ++m)
#pragma unroll
      for (int n = 0; n < 4; ++n)
        acc[4 + m][n] = mfma16(a1[m], b1[n], acc[4 + m][n]);
    __builtin_amdgcn_s_setprio(0);
    __builtin_amdgcn_s_barrier();
    cur = nxt;
  }
}

// ---- fused QKV: X[8192,1024] x {Wq,Wk,Wv}^T. BM256xBN128, grid 768. ----
__global__ __launch_bounds__(256, 2) void qkv_kernel(
    const unsigned short* __restrict__ X, const unsigned short* __restrict__ TQ,
    const unsigned short* __restrict__ TK, const unsigned short* __restrict__ TV,
    const float* __restrict__ bq, const float* __restrict__ bk,
    const float* __restrict__ bv, unsigned short* __restrict__ Q16,
    unsigned short* __restrict__ K16, unsigned short* __restrict__ VT) {
  __shared__ char lds[3 * 24576];
  const int wgid = swz8(blockIdx.x, 96);
  const int tm = wgid / 24, tn = wgid % 24;
  const int w = tn >> 3, c = tn & 7;
  const unsigned short* Bt = w == 0 ? TQ : (w == 1 ? TK : TV);
  const float* bias = w == 0 ? bq : (w == 1 ? bk : bv);

  f32x4 acc[8][4];
  gemm_core(X, Bt, 1024, 1024, 32, (long)tm * 256, (long)c * 128, lds, acc);

  const int tid = threadIdx.x, lane = tid & 63, wid = tid >> 6;
  const int wm = wid >> 1, wn = wid & 1;
  const int l15 = lane & 15, lhi = lane >> 4;
  const int rowBase = tm * 256 + wm * 128;
  const int colBase = c * 128 + wn * 64;  // within-weight column (D index)
  if (w < 2) {
    unsigned short* C = w == 0 ? Q16 : K16;
#pragma unroll
    for (int m = 0; m < 8; ++m)
#pragma unroll
      for (int n = 0; n < 4; ++n) {
        const int col = colBase + n * 16 + l15;
        const float bvv = bias[col];
#pragma unroll
        for (int j = 0; j < 4; ++j) {
          const int row = rowBase + m * 16 + lhi * 4 + j;
          C[(long)row * 1024 + col] = f2bf(acc[m][n][j] + bvv);
        }
      }
  } else {
#pragma unroll
    for (int m = 0; m < 8; ++m)
#pragma unroll
      for (int n = 0; n < 4; ++n) {
        const int col = colBase + n * 16 + l15;
        const float bvv = bias[col];
        const int row0 = rowBase + m * 16 + lhi * 4;
        const int b = row0 >> 11, s = row0 & 2047;
        u16x4 v;
#pragma unroll
        for (int j = 0; j < 4; ++j) v[j] = f2bf(acc[m][n][j] + bvv);
        *reinterpret_cast<u16x4*>(&VT[(long)b * 2097152 + (long)col * 2048 + s]) = v;
      }
  }
}

// ---- scores = Q K^T / 32 per batch, fp16 out. BM256xBN256 BK64, grid 256.
__global__ __launch_bounds__(512, 1) void scores_kernel(
    const unsigned short* __restrict__ Q16, const unsigned short* __restrict__ K16,
    unsigned short* __restrict__ SC16) {
  extern __shared__ char lds[];  // 131072 bytes
  const int wgid = swz8(blockIdx.x, 32);
  const int bz = wgid >> 6, tm = (wgid >> 3) & 7, tn = wgid & 7;
  const unsigned short* A = Q16 + (long)bz * 2097152;
  const unsigned short* Bt = K16 + (long)bz * 2097152;

  f32x4 acc[8][4];
  gemm_core3(A, Bt, 1024, 1024, 16, (long)tm * 256, (long)tn * 256, lds, acc);

  unsigned short* C = SC16 + (long)bz * 4194304;
  const int tid = threadIdx.x, lane = tid & 63, wid = tid >> 6;
  const int wm = wid >> 2, wn = wid & 3;
  const int l15 = lane & 15, lhi = lane >> 4;
  const int rowBase = tm * 256 + wm * 128;
  const int colBase = tn * 256 + wn * 64;
#pragma unroll
  for (int m = 0; m < 8; ++m)
#pragma unroll
    for (int n = 0; n < 4; ++n) {
      const int col = colBase + n * 16 + l15;
#pragma unroll
      for (int j = 0; j < 4; ++j) {
        const int row = rowBase + m * 16 + lhi * 4 + j;
        C[(long)row * 2048 + col] = f2h(acc[m][n][j] * (1.f / 32.f));
      }
    }
}

// ---- out = P V per batch (Bt = VT[D][S]). BM256xBN128, grid 256. ----
__global__ __launch_bounds__(256, 2) void pv_kernel(
    const unsigned short* __restrict__ P16, const unsigned short* __restrict__ VT,
    float* __restrict__ out) {
  __shared__ char lds[3 * 24576];
  const int wgid = swz8(blockIdx.x, 32);
  const int bz = wgid >> 6, tm = (wgid >> 3) & 7, tn = wgid & 7;
  const unsigned short* A = P16 + (long)bz * 4194304;
  const unsigned short* Bt = VT + (long)bz * 2097152;

  f32x4 acc[8][4];
  gemm_core(A, Bt, 2048, 2048, 64, (long)tm * 256, (long)tn * 128, lds, acc);

  float* C = out + (long)bz * 2097152;
  const int tid = threadIdx.x, lane = tid & 63, wid = tid >> 6;
  const int wm = wid >> 1, wn = wid & 1;
  const int l15 = lane & 15, lhi = lane >> 4;
  const int rowBase = tm * 256 + wm * 128;
  const int colBase = tn * 128 + wn * 64;
#pragma unroll
  for (int m = 0; m < 8; ++m)
#pragma unroll
    for (int n = 0; n < 4; ++n) {
      const int col = colBase + n * 16 + l15;
#pragma unroll
      for (int j = 0; j < 4; ++j) {
        const int row = rowBase + m * 16 + lhi * 4 + j;
        C[(long)row * 1024 + col] = acc[m][n][j];
      }
    }
}

// ---- fp32 -> bf16, 4 elems/thread ----
__global__ __launch_bounds__(256) void cvt4(const float* __restrict__ in,
                                            unsigned short* __restrict__ out) {
  int i = blockIdx.x * 256 + threadIdx.x;
  float4 v = reinterpret_cast<const float4*>(in)[i];
  u16x4 r;
  r[0] = f2bf(v.x); r[1] = f2bf(v.y); r[2] = f2bf(v.z); r[3] = f2bf(v.w);
  reinterpret_cast<u16x4*>(out)[i] = r;
}

// ---- W [K,N] fp32 -> Wt [N,K] bf16 ----
__global__ __launch_bounds__(256) void cvtWt(
    const float* __restrict__ w0, const float* __restrict__ w1, const float* __restrict__ w2,
    unsigned short* __restrict__ t0, unsigned short* __restrict__ t1, unsigned short* __restrict__ t2) {
  const float* w = blockIdx.y == 0 ? w0 : (blockIdx.y == 1 ? w1 : w2);
  unsigned short* t = blockIdx.y == 0 ? t0 : (blockIdx.y == 1 ? t1 : t2);
  int id = blockIdx.x * 256 + threadIdx.x;
  int k = id >> 10, n = id & 1023;
  t[n * 1024 + k] = f2bf(w[id]);
}

// ---- row softmax: fp16 scores -> bf16 P.  One block per row (8 elems/thr).
__global__ __launch_bounds__(256) void softmax_rows(const unsigned short* __restrict__ S,
                                                    unsigned short* __restrict__ P) {
  const long row = blockIdx.x;
  const u16x8* src = reinterpret_cast<const u16x8*>(S + row * 2048);
  const int tid = threadIdx.x;
  u16x8 a = src[tid];
  float v[8];
#pragma unroll
  for (int i = 0; i < 8; ++i) v[i] = h2f(a[i]);
  float m = v[0];
#pragma unroll
  for (int i = 1; i < 8; ++i) m = fmaxf(m, v[i]);
#pragma unroll
  for (int o = 32; o > 0; o >>= 1) m = fmaxf(m, __shfl_xor(m, o));
  __shared__ float red[8];
  const int wid = tid >> 6, lane = tid & 63;
  if (lane == 0) red[wid] = m;
  __syncthreads();
  m = fmaxf(fmaxf(red[0], red[1]), fmaxf(red[2], red[3]));
  float s = 0.f;
#pragma unroll
  for (int i = 0; i < 8; ++i) { v[i] = __expf(v[i] - m); s += v[i]; }
#pragma unroll
  for (int o = 32; o > 0; o >>= 1) s += __shfl_xor(s, o);
  if (lane == 0) red[4 + wid] = s;
  __syncthreads();
  s = (red[4] + red[5]) + (red[6] + red[7]);
  const float inv = 1.f / s;
  u16x8 p;
#pragma unroll
  for (int i = 0; i < 8; ++i) p[i] = f2bf(v[i] * inv);
  reinterpret_cast<u16x8*>(P + row * 2048)[tid] = p;
}

extern "C" void kernel_launch(void* const* d_in, const int* in_sizes, int n_in,
                              void* d_out, int out_size, void* d_ws, size_t ws_size,
                              hipStream_t stream) {
  const float* x  = (const float*)d_in[0];
  const float* Wq = (const float*)d_in[1];
  const float* bq = (const float*)d_in[2];
  const float* Wk = (const float*)d_in[3];
  const float* bk = (const float*)d_in[4];
  const float* Wv = (const float*)d_in[5];
  const float* bv = (const float*)d_in[6];
  float* out = (float*)d_out;

  char* ws = (char*)d_ws;
  const size_t MB = 1024 * 1024;
  unsigned short* X16 = (unsigned short*)(ws);
  unsigned short* TQ  = (unsigned short*)(ws + 16 * MB);
  unsigned short* TK  = (unsigned short*)(ws + 18 * MB);
  unsigned short* TV  = (unsigned short*)(ws + 20 * MB);
  unsigned short* Q16 = (unsigned short*)(ws + 22 * MB);
  unsigned short* K16 = (unsigned short*)(ws + 38 * MB);
  unsigned short* VT  = (unsigned short*)(ws + 54 * MB);
  unsigned short* SC16 = (unsigned short*)(ws + 70 * MB);
  unsigned short* P16 = Q16;  // alias Q16+K16 (32MB), dead after scores GEMM

  // allow 128KB dynamic LDS for scores_kernel (host-side attr, not captured)
  static bool attr_set = false;
  if (!attr_set) {
    hipFuncSetAttribute(reinterpret_cast<const void*>(scores_kernel),
                        hipFuncAttributeMaxDynamicSharedMemorySize, 131072);
    attr_set = true;
  }

  cvt4<<<8192, 256, 0, stream>>>(x, X16);
  cvtWt<<<dim3(4096, 3), 256, 0, stream>>>(Wq, Wk, Wv, TQ, TK, TV);

  qkv_kernel<<<768, 256, 0, stream>>>(X16, TQ, TK, TV, bq, bk, bv, Q16, K16, VT);
  scores_kernel<<<256, 512, 131072, stream>>>(Q16, K16, SC16);
  softmax_rows<<<4 * 2048, 256, 0, stream>>>(SC16, P16);
  pv_kernel<<<256, 256, 0, stream>>>(P16, VT, out);

  (void)in_sizes; (void)n_in; (void)out_size; (void)ws_size;
}